// Round 6
// baseline (202.778 us; speedup 1.0000x reference)
//
#include <hip/hip_runtime.h>
#include <hip/hip_bf16.h>

// SelfAttention: O = softmax(mask((X_q WQ)(X_k WK)^T/8)) (X_v WV), causal +
// key-padding (V_len) + query (Q_len) masks. B=8 S=1024 D=1024 H=16 Dh=64.
//
// All intermediates FP16 (11-bit mantissa, same MFMA rate as bf16). Values fit
// fp16 range: |q|<=0.5 (1/8 folded), |k|,|v|<=4, p=exp(s)<=~150 << 65504.
//
// Pipeline:
//   proj_gemm_all: ONE dispatch, 1536 blocks x 512 threads. slice 0/1 ->
//                  q_proj/k_proj [B][H][S][Dh], slice 2 -> vT [B][H][Dh][S].
//                  BK=64, single LDS buffer, REGISTER PREFETCH across the
//                  barrier: step t+1's global loads issue before step t's
//                  MFMA phase (latency hidden), cvt+ds_write after barrier.
//                  m-fast block order keeps one W slab L2-resident.
//   attn_fwd     : flash attention, shift-free softmax, vlen tile skipping,
//                  masks only on final tiles. Block = (b,h,z) handles q-tiles
//                  {15-z, z} in ONE fused KV sweep (K/V tiles loaded once,
//                  feed both halves).

#define B_  8
#define S_  1024
#define D_  1024
#define H_  16
#define DH_ 64

using f16x8  = __attribute__((ext_vector_type(8))) _Float16;
using s16x8  = __attribute__((ext_vector_type(8))) short;
using f32x4  = __attribute__((ext_vector_type(4))) float;
using s16x4  = __attribute__((ext_vector_type(4))) short;

__device__ inline short f2h(float x) {
  _Float16 h = (_Float16)x;  // RNE
  return __builtin_bit_cast(short, h);
}

__device__ inline f16x8 ld_frag_lds(const short* p) {  // p must be 8B aligned
  s16x4 a = *(const s16x4*)p;
  s16x4 b = *(const s16x4*)(p + 4);
  s16x8 r = {a[0], a[1], a[2], a[3], b[0], b[1], b[2], b[3]};
  return __builtin_bit_cast(f16x8, r);
}

__device__ inline f16x8 ld_frag_g(const short* p) {  // 16B aligned
  return __builtin_bit_cast(f16x8, *(const s16x8*)p);
}

__device__ inline void st8h(short* p, const float* v) {  // 8 floats -> 2x8B
  s16x4 a = {f2h(v[0]), f2h(v[1]), f2h(v[2]), f2h(v[3])};
  s16x4 b = {f2h(v[4]), f2h(v[5]), f2h(v[6]), f2h(v[7])};
  *(s16x4*)p = a;
  *(s16x4*)(p + 4) = b;
}

// ---------------------------------------------------------------- projections
// 3 slices x 512 blocks, 512 threads (8 waves 2x4), tile 128x128, BK=64.
// mode 0: C = X @ W          (direct-stage X rows -> As, trans-stage W -> Bs)
// mode 1: C = W^T @ X^T      (trans-stage W -> As, direct-stage X rows -> Bs)
// LDP=68: 136B rows -> odd dword stride (34), 8B aligned, <=4-way conflicts.
#define LDP 68
#define BK  64

__global__ __launch_bounds__(512, 4) void proj_gemm_all(
    const float* __restrict__ Qx, const float* __restrict__ Kx,
    const float* __restrict__ Vx, const float* __restrict__ WQ,
    const float* __restrict__ WK, const float* __restrict__ WV,
    short* __restrict__ qp, short* __restrict__ kp, short* __restrict__ vp) {
  __shared__ short As[128][LDP];
  __shared__ short Bs[128][LDP];
  const int gid = blockIdx.x;
  const int slice = gid >> 9;
  const int r = gid & 511;

  const float* X;
  const float* W;
  short* out;
  float oscale;
  int mode;
  if (slice == 0) {
    X = Qx; W = WQ; out = qp; oscale = 0.125f; mode = 0;
  } else if (slice == 1) {
    X = Kx; W = WK; out = kp; oscale = 1.0f; mode = 0;
  } else {
    X = Vx; W = WV; out = vp; oscale = 1.0f; mode = 1;
  }
  const int m0 = (mode == 0 ? (r & 63) : (r & 7)) * 128;
  const int n0 = (mode == 0 ? (r >> 6) : (r >> 3)) * 128;

  // direct-stage: 128 rows of X starting drow0 -> Ds[row][k]
  // trans-stage : 128 cols of W starting tcol0 -> Ts[col][k]
  short(*Ds)[LDP] = (mode == 0) ? As : Bs;
  short(*Ts)[LDP] = (mode == 0) ? Bs : As;
  const int drow0 = (mode == 0) ? m0 : n0;
  const int tcol0 = (mode == 0) ? n0 : m0;

  const int tid = threadIdx.x;
  const int lane = tid & 63;
  const int w = tid >> 6;
  const int wr = w >> 2, wc = w & 3;  // 2 x 4 waves, each 64x32 output
  const int lr = lane & 15, lg = lane >> 4;

  // staging maps (per thread, per K-step)
  const int d_row = tid >> 2;            // 0..127
  const int d_q = tid & 3;               // 16-col segment
  const int t_col = tid & 127;           // 0..127
  const int t_kh = (tid >> 7) * 16;      // 0,16,32,48

  f32x4 acc[4][2];
#pragma unroll
  for (int i = 0; i < 4; ++i)
#pragma unroll
    for (int j = 0; j < 2; ++j) acc[i][j] = f32x4{0.f, 0.f, 0.f, 0.f};

  float4 dreg[4];
  float treg[16];

  // ---- prologue: stage step 0
#pragma unroll
  for (int j = 0; j < 4; ++j)
    dreg[j] = *(const float4*)(X + (size_t)(drow0 + d_row) * D_ + d_q * 16 +
                               j * 4);
#pragma unroll
  for (int kk = 0; kk < 16; ++kk)
    treg[kk] = W[(size_t)(t_kh + kk) * D_ + tcol0 + t_col];
  {
    float tmp[16];
#pragma unroll
    for (int j = 0; j < 4; ++j) {
      tmp[j * 4 + 0] = dreg[j].x; tmp[j * 4 + 1] = dreg[j].y;
      tmp[j * 4 + 2] = dreg[j].z; tmp[j * 4 + 3] = dreg[j].w;
    }
    st8h(&Ds[d_row][d_q * 16], tmp);
    st8h(&Ds[d_row][d_q * 16 + 8], tmp + 8);
    st8h(&Ts[t_col][t_kh], treg);
    st8h(&Ts[t_col][t_kh + 8], treg + 8);
  }
  __syncthreads();

  for (int kt = 0; kt < D_ / BK; ++kt) {
    const bool more = (kt + 1) < (D_ / BK);
    const int k1 = (kt + 1) * BK;
    // ---- issue next step's global loads (latency hides under MFMA)
    if (more) {
#pragma unroll
      for (int j = 0; j < 4; ++j)
        dreg[j] = *(const float4*)(X + (size_t)(drow0 + d_row) * D_ + k1 +
                                   d_q * 16 + j * 4);
#pragma unroll
      for (int kk = 0; kk < 16; ++kk)
        treg[kk] = W[(size_t)(k1 + t_kh + kk) * D_ + tcol0 + t_col];
    }

    // ---- MFMA phase on current LDS tile
#pragma unroll
    for (int c = 0; c < 2; ++c) {
      f16x8 af[4], bf[2];
#pragma unroll
      for (int mi = 0; mi < 4; ++mi)
        af[mi] = ld_frag_lds(&As[wr * 64 + mi * 16 + lr][c * 32 + lg * 8]);
#pragma unroll
      for (int ni = 0; ni < 2; ++ni)
        bf[ni] = ld_frag_lds(&Bs[wc * 32 + ni * 16 + lr][c * 32 + lg * 8]);
#pragma unroll
      for (int mi = 0; mi < 4; ++mi)
#pragma unroll
        for (int ni = 0; ni < 2; ++ni)
          acc[mi][ni] = __builtin_amdgcn_mfma_f32_16x16x32_f16(
              af[mi], bf[ni], acc[mi][ni], 0, 0, 0);
    }
    __syncthreads();  // all waves done reading LDS

    // ---- convert + write next tile
    if (more) {
      float tmp[16];
#pragma unroll
      for (int j = 0; j < 4; ++j) {
        tmp[j * 4 + 0] = dreg[j].x; tmp[j * 4 + 1] = dreg[j].y;
        tmp[j * 4 + 2] = dreg[j].z; tmp[j * 4 + 3] = dreg[j].w;
      }
      st8h(&Ds[d_row][d_q * 16], tmp);
      st8h(&Ds[d_row][d_q * 16 + 8], tmp + 8);
      st8h(&Ts[t_col][t_kh], treg);
      st8h(&Ts[t_col][t_kh + 8], treg + 8);
      __syncthreads();  // writes visible before next MFMA phase
    }
  }

  // ---- epilogue
#pragma unroll
  for (int mi = 0; mi < 4; ++mi)
#pragma unroll
    for (int ni = 0; ni < 2; ++ni) {
      const int mgb = m0 + wr * 64 + mi * 16 + lg * 4;
      const int ng = n0 + wc * 32 + ni * 16 + lr;
#pragma unroll
      for (int reg = 0; reg < 4; ++reg) {
        const int m = mgb + reg;
        const short val = f2h(acc[mi][ni][reg] * oscale);
        if (mode == 0) {
          const int b = m >> 10, s = m & 1023, hh = ng >> 6, dh = ng & 63;
          out[((size_t)((b * H_ + hh) * S_) + s) * DH_ + dh] = val;
        } else {
          const int hh = m >> 6, dh = m & 63, b = ng >> 10, s = ng & 1023;
          out[((size_t)((b * H_ + hh) * DH_) + dh) * S_ + s] = val;
        }
      }
    }
}

// ----------------------------------------------------------------- attention
// Block = (b, h, z): q-tiles {qtH=15-z, qtL=z}, ONE fused sweep over KV tiles
// t = 0..nTH-1; the light half participates while t < nTL, so shared tiles
// are loaded once and feed both halves' QK^T and PV MFMAs.
// Shift-free softmax (p = exp(s); exp(s - 1e12) == 0.0f exactly). Tiles with
// kv0 >= vlen skipped (vlen>0); vlen==0 degrades to plain causal softmax.
// Mask predication only where needed (own causal tile / vlen boundary tile).
__global__ __launch_bounds__(256, 2) void attn_fwd(
    const short* __restrict__ qp, const short* __restrict__ kp,
    const short* __restrict__ vT, const int* __restrict__ Qlen,
    const int* __restrict__ Vlen, float* __restrict__ out) {
  __shared__ short Plds[2][4][16][72];  // [half][wave] private P tiles
  const int bid = blockIdx.x;
  const int z = bid & 7;
  const int bh = bid >> 3;
  const int h = bh & 15;
  const int b = bh >> 4;
  const int lane = threadIdx.x & 63;
  const int w = threadIdx.x >> 6;
  const int lr = lane & 15, lg = lane >> 4;
  const short* qb = qp + (size_t)((b * H_ + h) * S_) * DH_;
  const short* kb = kp + (size_t)((b * H_ + h) * S_) * DH_;
  const short* vb = vT + (size_t)((b * H_ + h) * DH_) * S_;
  const int vlen = Vlen[b], qlen = Qlen[b];

  const int qtH = 15 - z, qtL = z;
  const int vcap = (vlen + 63) >> 6;
  const int nTH = (vlen > 0) ? min(qtH + 1, vcap) : (qtH + 1);
  const int nTL = (vlen > 0) ? min(qtL + 1, vcap) : (qtL + 1);
  const int q0H = qtH * 64 + w * 16;
  const int q0L = qtL * 64 + w * 16;

  f16x8 qfH[2], qfL[2];
#pragma unroll
  for (int c = 0; c < 2; ++c) {
    qfH[c] = ld_frag_g(qb + (size_t)(q0H + lr) * DH_ + c * 32 + lg * 8);
    qfL[c] = ld_frag_g(qb + (size_t)(q0L + lr) * DH_ + c * 32 + lg * 8);
  }

  float lH[4], lL[4];
  f32x4 oH[4], oL[4];
#pragma unroll
  for (int rr = 0; rr < 4; ++rr) {
    lH[rr] = 0.f; lL[rr] = 0.f;
    oH[rr] = f32x4{0.f, 0.f, 0.f, 0.f};
    oL[rr] = f32x4{0.f, 0.f, 0.f, 0.f};
  }

  f16x8 kf[8];  // current K tile fragments [nt*2+c]
#pragma unroll
  for (int nt = 0; nt < 4; ++nt)
#pragma unroll
    for (int c = 0; c < 2; ++c)
      kf[nt * 2 + c] =
          ld_frag_g(kb + (size_t)(nt * 16 + lr) * DH_ + c * 32 + lg * 8);

  for (int t = 0; t < nTH; ++t) {
    const int kv0 = t * 64;
    const int kvn = (t + 1 < nTH) ? kv0 + 64 : kv0;  // clamped prefetch
    const bool lact = t < nTL;

    f16x8 vf[8];  // V for THIS tile — issued before QK/softmax
#pragma unroll
    for (int dt = 0; dt < 4; ++dt)
#pragma unroll
      for (int c = 0; c < 2; ++c)
        vf[dt * 2 + c] =
            ld_frag_g(vb + (size_t)(dt * 16 + lr) * S_ + kv0 + c * 32 + lg * 8);

    f16x8 kn[8];  // K for NEXT tile
#pragma unroll
    for (int nt = 0; nt < 4; ++nt)
#pragma unroll
      for (int c = 0; c < 2; ++c)
        kn[nt * 2 + c] = ld_frag_g(kb + (size_t)(kvn + nt * 16 + lr) * DH_ +
                                   c * 32 + lg * 8);

    // ---- QK^T phase (both halves: up to 16 independent MFMAs)
    f32x4 sH[4], sL[4];
#pragma unroll
    for (int nt = 0; nt < 4; ++nt) sH[nt] = f32x4{0.f, 0.f, 0.f, 0.f};
#pragma unroll
    for (int nt = 0; nt < 4; ++nt)
#pragma unroll
      for (int c = 0; c < 2; ++c)
        sH[nt] = __builtin_amdgcn_mfma_f32_16x16x32_f16(qfH[c], kf[nt * 2 + c],
                                                        sH[nt], 0, 0, 0);
    if (lact) {
#pragma unroll
      for (int nt = 0; nt < 4; ++nt) sL[nt] = f32x4{0.f, 0.f, 0.f, 0.f};
#pragma unroll
      for (int nt = 0; nt < 4; ++nt)
#pragma unroll
        for (int c = 0; c < 2; ++c)
          sL[nt] = __builtin_amdgcn_mfma_f32_16x16x32_f16(
              qfL[c], kf[nt * 2 + c], sL[nt], 0, 0, 0);
    }

    const bool km = (vlen > 0) && (vlen - kv0 < 64);  // vlen boundary tile

    // ---- softmax phase (heavy)
    if ((t == qtH) | km) {
#pragma unroll
      for (int reg = 0; reg < 4; ++reg) {
        const int qrow = q0H + lg * 4 + reg;
#pragma unroll
        for (int nt = 0; nt < 4; ++nt) {
          const int kv = kv0 + nt * 16 + lr;
          float sv = sH[nt][reg];
          if (km && kv >= vlen) sv -= 1e12f;  // key padding -> exp == 0
          if (kv > qrow) sv -= 1e12f;         // causal -> exp == 0
          const float p = __expf(sv);
          lH[reg] += p;
          Plds[0][w][lg * 4 + reg][nt * 16 + lr] = f2h(p);
        }
      }
    } else {
#pragma unroll
      for (int reg = 0; reg < 4; ++reg)
#pragma unroll
        for (int nt = 0; nt < 4; ++nt) {
          const float p = __expf(sH[nt][reg]);
          lH[reg] += p;
          Plds[0][w][lg * 4 + reg][nt * 16 + lr] = f2h(p);
        }
    }
    // ---- softmax phase (light)
    if (lact) {
      if ((t == qtL) | km) {
#pragma unroll
        for (int reg = 0; reg < 4; ++reg) {
          const int qrow = q0L + lg * 4 + reg;
#pragma unroll
          for (int nt = 0; nt < 4; ++nt) {
            const int kv = kv0 + nt * 16 + lr;
            float sv = sL[nt][reg];
            if (km && kv >= vlen) sv -= 1e12f;
            if (kv > qrow) sv -= 1e12f;
            const float p = __expf(sv);
            lL[reg] += p;
            Plds[1][w][lg * 4 + reg][nt * 16 + lr] = f2h(p);
          }
        }
      } else {
#pragma unroll
        for (int reg = 0; reg < 4; ++reg)
#pragma unroll
          for (int nt = 0; nt < 4; ++nt) {
            const float p = __expf(sL[nt][reg]);
            lL[reg] += p;
            Plds[1][w][lg * 4 + reg][nt * 16 + lr] = f2h(p);
          }
      }
    }

    // ---- PV phase (both halves share vf)
#pragma unroll
    for (int c = 0; c < 2; ++c) {
      f16x8 paH = ld_frag_lds(&Plds[0][w][lr][c * 32 + lg * 8]);
#pragma unroll
      for (int dt = 0; dt < 4; ++dt)
        oH[dt] = __builtin_amdgcn_mfma_f32_16x16x32_f16(paH, vf[dt * 2 + c],
                                                        oH[dt], 0, 0, 0);
    }
    if (lact) {
#pragma unroll
      for (int c = 0; c < 2; ++c) {
        f16x8 paL = ld_frag_lds(&Plds[1][w][lr][c * 32 + lg * 8]);
#pragma unroll
        for (int dt = 0; dt < 4; ++dt)
          oL[dt] = __builtin_amdgcn_mfma_f32_16x16x32_f16(paL, vf[dt * 2 + c],
                                                          oL[dt], 0, 0, 0);
      }
    }

#pragma unroll
    for (int i = 0; i < 8; ++i) kf[i] = kn[i];
  }

  // ---- epilogue: both halves
#pragma unroll
  for (int reg = 0; reg < 4; ++reg) {
    float ls = lH[reg];
    ls += __shfl_xor(ls, 1);
    ls += __shfl_xor(ls, 2);
    ls += __shfl_xor(ls, 4);
    ls += __shfl_xor(ls, 8);
    const int qrow = q0H + lg * 4 + reg;
    const float sc = (qrow < qlen) ? (1.f / ls) : 0.f;
#pragma unroll
    for (int dt = 0; dt < 4; ++dt)
      out[(size_t)(b * S_ + qrow) * D_ + h * DH_ + dt * 16 + lr] =
          oH[dt][reg] * sc;
  }
#pragma unroll
  for (int reg = 0; reg < 4; ++reg) {
    float ls = lL[reg];
    ls += __shfl_xor(ls, 1);
    ls += __shfl_xor(ls, 2);
    ls += __shfl_xor(ls, 4);
    ls += __shfl_xor(ls, 8);
    const int qrow = q0L + lg * 4 + reg;
    const float sc = (qrow < qlen) ? (1.f / ls) : 0.f;
#pragma unroll
    for (int dt = 0; dt < 4; ++dt)
      out[(size_t)(b * S_ + qrow) * D_ + h * DH_ + dt * 16 + lr] =
          oL[dt][reg] * sc;
  }
}

// ------------------------------------------------------------------- launch
extern "C" void kernel_launch(void* const* d_in, const int* in_sizes, int n_in,
                              void* d_out, int out_size, void* d_ws,
                              size_t ws_size, hipStream_t stream) {
  const float* Q = (const float*)d_in[0];
  const float* K = (const float*)d_in[1];
  const float* V = (const float*)d_in[2];
  const float* WQ = (const float*)d_in[3];
  const float* WK = (const float*)d_in[4];
  const float* WV = (const float*)d_in[5];
  const int* Qlen = (const int*)d_in[6];
  const int* Vlen = (const int*)d_in[7];
  float* out = (float*)d_out;

  const size_t PE = (size_t)B_ * H_ * S_ * DH_;  // 8388608 elements
  short* qp = (short*)d_ws;
  short* kp = qp + PE;
  short* vT = kp + PE;  // total 48 MiB of d_ws

  proj_gemm_all<<<dim3(1536), dim3(512), 0, stream>>>(Q, K, V, WQ, WK, WV, qp,
                                                      kp, vT);
  attn_fwd<<<dim3(1024), dim3(256), 0, stream>>>(qp, kp, vT, Qlen, Vlen, out);
}

// Round 8
// 172.056 us; speedup vs baseline: 1.1786x; 1.1786x over previous
//
#include <hip/hip_runtime.h>
#include <hip/hip_bf16.h>

// SelfAttention: O = softmax(mask((X_q WQ)(X_k WK)^T/8)) (X_v WV), causal +
// key-padding (V_len) + query (Q_len) masks. B=8 S=1024 D=1024 H=16 Dh=64.
//
// All intermediates FP16. Pipeline:
//   wt_prep : Wt[3][n][k] = W[k][n] fp16 (transpose+convert, ~18MB traffic)
//   proj<0> : q_proj/k_proj = X @ W     via A=X(fp32,cvt-stage), B=Wt(gload_lds)
//   proj<1> : vT = (Xv Wv)^T = Wv^T Xv^T via A=Wt(gload_lds), B=Xv(cvt-stage)
//             m97-style K-loop: BK=32, LDS double-buffer, ONE barrier/step,
//             global_load_lds width 16 for the fp16 operand (no VGPR roundtrip
//             -> compiler can't sink it; loads overlap MFMA).
//   attn_fwd: flash attention, shift-free softmax, vlen tile skipping, fused
//             q-tile pairs {15-z, z} per block (K/V tiles loaded once).

#define B_  8
#define S_  1024
#define D_  1024
#define H_  16
#define DH_ 64

using f16x8  = __attribute__((ext_vector_type(8))) _Float16;
using h16x2  = __attribute__((ext_vector_type(2))) __fp16;  // cvt_pkrtz result
using s16x8  = __attribute__((ext_vector_type(8))) short;
using f32x4  = __attribute__((ext_vector_type(4))) float;
using s16x4  = __attribute__((ext_vector_type(4))) short;
using u32x4  = __attribute__((ext_vector_type(4))) unsigned int;

__device__ inline short f2h(float x) {
  _Float16 h = (_Float16)x;  // RNE
  return __builtin_bit_cast(short, h);
}

__device__ inline unsigned pk2(float a, float b) {  // 2 fp32 -> packed 2xfp16
  h16x2 p = __builtin_amdgcn_cvt_pkrtz(a, b);
  return __builtin_bit_cast(unsigned, p);
}

__device__ inline f16x8 ld_frag_g(const short* p) {  // 16B aligned
  return __builtin_bit_cast(f16x8, *(const s16x8*)p);
}

#define GLOAD_LDS16(gsrc, ldst)                                              \
  __builtin_amdgcn_global_load_lds(                                          \
      (const __attribute__((address_space(1))) unsigned int*)(gsrc),         \
      (__attribute__((address_space(3))) unsigned int*)(ldst), 16, 0, 0)

// ------------------------------------------------------------- W transpose
// Wt[slice][n][k] = W_slice[k][n], fp32 -> fp16. 64x64 tiles.
__global__ __launch_bounds__(256) void wt_prep(const float* __restrict__ WQ,
                                               const float* __restrict__ WK,
                                               const float* __restrict__ WV,
                                               short* __restrict__ wt) {
  __shared__ float t[64][65];
  const int slice = blockIdx.z;
  const float* W = (slice == 0) ? WQ : (slice == 1) ? WK : WV;
  const int k0 = blockIdx.y * 64, n0 = blockIdx.x * 64;
  const int tid = threadIdx.x;
  {
    const int r = tid >> 2, c4 = tid & 3;  // 16 floats per thread
#pragma unroll
    for (int j = 0; j < 4; ++j) {
      float4 v = *(const float4*)(W + (size_t)(k0 + r) * D_ + n0 + c4 * 16 +
                                  j * 4);
      t[r][c4 * 16 + j * 4 + 0] = v.x;
      t[r][c4 * 16 + j * 4 + 1] = v.y;
      t[r][c4 * 16 + j * 4 + 2] = v.z;
      t[r][c4 * 16 + j * 4 + 3] = v.w;
    }
  }
  __syncthreads();
  {
    const int rn = tid >> 2, ks = tid & 3;  // 16 k's per thread
    short* dst =
        wt + ((size_t)slice << 20) + (size_t)(n0 + rn) * D_ + k0 + ks * 16;
    s16x4 h[4];
#pragma unroll
    for (int g = 0; g < 4; ++g)
#pragma unroll
      for (int j = 0; j < 4; ++j) h[g][j] = f2h(t[ks * 16 + g * 4 + j][rn]);
    *(s16x4*)(dst + 0) = h[0];
    *(s16x4*)(dst + 4) = h[1];
    *(s16x4*)(dst + 8) = h[2];
    *(s16x4*)(dst + 12) = h[3];
  }
}

// ---------------------------------------------------------------- projections
// 128x128 tile, BK=32, 256 threads (4 waves 2x2, wave tile 64x64 = 4x4 frags).
// Fs: fp32-converted operand, padded [128][40] (conflict-free, reg-staged).
// Gs: Wt operand, linear [128][32], staged by global_load_lds width 16.
// Double-buffered; one __syncthreads per K-step; next step's loads issue
// before current step's MFMA phase.
template <int MODE>
__global__ __launch_bounds__(256, 3) void proj(
    const float* __restrict__ Qx, const float* __restrict__ Kx,
    const float* __restrict__ Vx, const short* __restrict__ wt,
    short* __restrict__ qp, short* __restrict__ kp, short* __restrict__ vp) {
  __shared__ __align__(16) short Fs[2][128][40];
  __shared__ __align__(16) short Gs[2][128][32];

  const int gid = blockIdx.x;
  const float* X;
  const short* Wtb;
  short* out;
  float oscale;
  int m0, n0, frow0, grow0;
  if (MODE == 0) {
    const int slice = gid >> 9, r = gid & 511;
    X = slice ? Kx : Qx;
    Wtb = wt + ((size_t)slice << 20);
    out = slice ? kp : qp;
    oscale = slice ? 1.0f : 0.125f;
    m0 = (r & 63) * 128;   // token dim (m-fast: 64 blocks share one Wt slab)
    n0 = (r >> 6) * 128;   // H*Dh dim
    frow0 = m0;            // Fs rows = X tokens
    grow0 = n0;            // Gs rows = Wt rows
  } else {
    const int b = gid >> 6, sub = gid & 63;
    X = Vx;
    Wtb = wt + ((size_t)2 << 20);
    out = vp + ((size_t)b << 20);  // vT slice for this b: [1024][1024]
    oscale = 1.0f;
    m0 = (sub & 7) * 128;          // H*Dh dim (fast: 8 blocks share X slab)
    n0 = (sub >> 3) * 128;         // token dim within batch b
    frow0 = (b << 10) + n0;        // Fs rows = Xv tokens
    grow0 = m0;                    // Gs rows = Wt_V rows
  }

  const int tid = threadIdx.x;
  const int lane = tid & 63;
  const int w = tid >> 6;
  const int wr = w >> 1, wc = w & 1;
  const int lr = lane & 15, lg = lane >> 4;

  // staging maps
  const int f_row = tid >> 1, f_seg = tid & 1;        // 16 f16 per thread
  const int g_row0 = tid >> 2, g_c = tid & 3;         // 2 gloads per thread

  f32x4 acc[4][4];
#pragma unroll
  for (int i = 0; i < 4; ++i)
#pragma unroll
    for (int j = 0; j < 4; ++j) acc[i][j] = f32x4{0.f, 0.f, 0.f, 0.f};

  const float* fbase = X + (size_t)(frow0 + f_row) * D_ + f_seg * 16;
  const short* gbase = Wtb + (size_t)(grow0 + g_row0) * D_ + g_c * 8;

  float4 fr[2], fr2[2];
  // ---- prologue: stage step 0
  GLOAD_LDS16(gbase, &Gs[0][g_row0][g_c * 8]);
  GLOAD_LDS16(gbase + (size_t)64 * D_, &Gs[0][g_row0 + 64][g_c * 8]);
  fr[0] = *(const float4*)(fbase + 0);
  fr[1] = *(const float4*)(fbase + 4);
  fr2[0] = *(const float4*)(fbase + 8);
  fr2[1] = *(const float4*)(fbase + 12);
  {
    u32x4 u = {pk2(fr[0].x, fr[0].y), pk2(fr[0].z, fr[0].w),
               pk2(fr[1].x, fr[1].y), pk2(fr[1].z, fr[1].w)};
    *(u32x4*)(&Fs[0][f_row][f_seg * 16]) = u;
    u32x4 u2 = {pk2(fr2[0].x, fr2[0].y), pk2(fr2[0].z, fr2[0].w),
                pk2(fr2[1].x, fr2[1].y), pk2(fr2[1].z, fr2[1].w)};
    *(u32x4*)(&Fs[0][f_row][f_seg * 16 + 8]) = u2;
  }
  __syncthreads();

  for (int kt = 0; kt < 32; ++kt) {
    const int cur = kt & 1, nxt = cur ^ 1;
    const bool more = kt < 31;
    const int k1 = (kt + 1) * 32;
    // ---- issue next-step loads (gload -> LDS direct; fp32 -> regs)
    if (more) {
      GLOAD_LDS16(gbase + k1, &Gs[nxt][g_row0][g_c * 8]);
      GLOAD_LDS16(gbase + (size_t)64 * D_ + k1, &Gs[nxt][g_row0 + 64][g_c * 8]);
      fr[0] = *(const float4*)(fbase + k1 + 0);
      fr[1] = *(const float4*)(fbase + k1 + 4);
      fr2[0] = *(const float4*)(fbase + k1 + 8);
      fr2[1] = *(const float4*)(fbase + k1 + 12);
    }

    // ---- MFMA phase on current buffers
    f16x8 af[4], bf[4];
#pragma unroll
    for (int mi = 0; mi < 4; ++mi)
      af[mi] = (MODE == 0)
                   ? ld_frag_g(&Fs[cur][wr * 64 + mi * 16 + lr][lg * 8])
                   : ld_frag_g(&Gs[cur][wr * 64 + mi * 16 + lr][lg * 8]);
#pragma unroll
    for (int ni = 0; ni < 4; ++ni)
      bf[ni] = (MODE == 0)
                   ? ld_frag_g(&Gs[cur][wc * 64 + ni * 16 + lr][lg * 8])
                   : ld_frag_g(&Fs[cur][wc * 64 + ni * 16 + lr][lg * 8]);
#pragma unroll
    for (int mi = 0; mi < 4; ++mi)
#pragma unroll
      for (int ni = 0; ni < 4; ++ni)
        acc[mi][ni] = __builtin_amdgcn_mfma_f32_16x16x32_f16(
            af[mi], bf[ni], acc[mi][ni], 0, 0, 0);

    // ---- convert + write next Fs tile
    if (more) {
      u32x4 u = {pk2(fr[0].x, fr[0].y), pk2(fr[0].z, fr[0].w),
                 pk2(fr[1].x, fr[1].y), pk2(fr[1].z, fr[1].w)};
      *(u32x4*)(&Fs[nxt][f_row][f_seg * 16]) = u;
      u32x4 u2 = {pk2(fr2[0].x, fr2[0].y), pk2(fr2[0].z, fr2[0].w),
                  pk2(fr2[1].x, fr2[1].y), pk2(fr2[1].z, fr2[1].w)};
      *(u32x4*)(&Fs[nxt][f_row][f_seg * 16 + 8]) = u2;
    }
    __syncthreads();  // drains gloads (vmcnt0) + Fs writes; buffers swap
  }

  // ---- epilogue
#pragma unroll
  for (int mi = 0; mi < 4; ++mi)
#pragma unroll
    for (int ni = 0; ni < 4; ++ni) {
      const int mgb = m0 + wr * 64 + mi * 16 + lg * 4;
      const int ng = n0 + wc * 64 + ni * 16 + lr;
#pragma unroll
      for (int reg = 0; reg < 4; ++reg) {
        const int m = mgb + reg;
        const short val = f2h(acc[mi][ni][reg] * oscale);
        if (MODE == 0) {
          const int b = m >> 10, s = m & 1023, hh = ng >> 6, dh = ng & 63;
          out[((size_t)((b * H_ + hh) * S_) + s) * DH_ + dh] = val;
        } else {
          out[(size_t)m * S_ + ng] = val;  // vT[b][m=h*64+dh][s=ng]
        }
      }
    }
}

// ----------------------------------------------------------------- attention
// Block = (b, h, z): q-tiles {qtH=15-z, qtL=z}, ONE fused sweep over KV tiles;
// shared K/V tiles loaded once feed both halves' QK^T and PV MFMAs.
// Shift-free softmax (p = exp(s); exp(s - 1e12) == 0.0f exactly). Tiles with
// kv0 >= vlen skipped (vlen>0); vlen==0 degrades to plain causal softmax.
__global__ __launch_bounds__(256, 2) void attn_fwd(
    const short* __restrict__ qp, const short* __restrict__ kp,
    const short* __restrict__ vT, const int* __restrict__ Qlen,
    const int* __restrict__ Vlen, float* __restrict__ out) {
  __shared__ short Plds[2][4][16][72];
  const int bid = blockIdx.x;
  const int z = bid & 7;
  const int bh = bid >> 3;
  const int h = bh & 15;
  const int b = bh >> 4;
  const int lane = threadIdx.x & 63;
  const int w = threadIdx.x >> 6;
  const int lr = lane & 15, lg = lane >> 4;
  const short* qb = qp + (size_t)((b * H_ + h) * S_) * DH_;
  const short* kb = kp + (size_t)((b * H_ + h) * S_) * DH_;
  const short* vb = vT + (size_t)((b * H_ + h) * DH_) * S_;
  const int vlen = Vlen[b], qlen = Qlen[b];

  const int qtH = 15 - z, qtL = z;
  const int vcap = (vlen + 63) >> 6;
  const int nTH = (vlen > 0) ? min(qtH + 1, vcap) : (qtH + 1);
  const int nTL = (vlen > 0) ? min(qtL + 1, vcap) : (qtL + 1);
  const int q0H = qtH * 64 + w * 16;
  const int q0L = qtL * 64 + w * 16;

  f16x8 qfH[2], qfL[2];
#pragma unroll
  for (int c = 0; c < 2; ++c) {
    qfH[c] = ld_frag_g(qb + (size_t)(q0H + lr) * DH_ + c * 32 + lg * 8);
    qfL[c] = ld_frag_g(qb + (size_t)(q0L + lr) * DH_ + c * 32 + lg * 8);
  }

  float lH[4], lL[4];
  f32x4 oH[4], oL[4];
#pragma unroll
  for (int rr = 0; rr < 4; ++rr) {
    lH[rr] = 0.f; lL[rr] = 0.f;
    oH[rr] = f32x4{0.f, 0.f, 0.f, 0.f};
    oL[rr] = f32x4{0.f, 0.f, 0.f, 0.f};
  }

  f16x8 kf[8];
#pragma unroll
  for (int nt = 0; nt < 4; ++nt)
#pragma unroll
    for (int c = 0; c < 2; ++c)
      kf[nt * 2 + c] =
          ld_frag_g(kb + (size_t)(nt * 16 + lr) * DH_ + c * 32 + lg * 8);

  for (int t = 0; t < nTH; ++t) {
    const int kv0 = t * 64;
    const int kvn = (t + 1 < nTH) ? kv0 + 64 : kv0;
    const bool lact = t < nTL;

    f16x8 vf[8];
#pragma unroll
    for (int dt = 0; dt < 4; ++dt)
#pragma unroll
      for (int c = 0; c < 2; ++c)
        vf[dt * 2 + c] =
            ld_frag_g(vb + (size_t)(dt * 16 + lr) * S_ + kv0 + c * 32 + lg * 8);

    f16x8 kn[8];
#pragma unroll
    for (int nt = 0; nt < 4; ++nt)
#pragma unroll
      for (int c = 0; c < 2; ++c)
        kn[nt * 2 + c] = ld_frag_g(kb + (size_t)(kvn + nt * 16 + lr) * DH_ +
                                   c * 32 + lg * 8);

    f32x4 sH[4], sL[4];
#pragma unroll
    for (int nt = 0; nt < 4; ++nt) sH[nt] = f32x4{0.f, 0.f, 0.f, 0.f};
#pragma unroll
    for (int nt = 0; nt < 4; ++nt)
#pragma unroll
      for (int c = 0; c < 2; ++c)
        sH[nt] = __builtin_amdgcn_mfma_f32_16x16x32_f16(qfH[c], kf[nt * 2 + c],
                                                        sH[nt], 0, 0, 0);
    if (lact) {
#pragma unroll
      for (int nt = 0; nt < 4; ++nt) sL[nt] = f32x4{0.f, 0.f, 0.f, 0.f};
#pragma unroll
      for (int nt = 0; nt < 4; ++nt)
#pragma unroll
        for (int c = 0; c < 2; ++c)
          sL[nt] = __builtin_amdgcn_mfma_f32_16x16x32_f16(
              qfL[c], kf[nt * 2 + c], sL[nt], 0, 0, 0);
    }

    const bool km = (vlen > 0) && (vlen - kv0 < 64);

    if ((t == qtH) | km) {
#pragma unroll
      for (int reg = 0; reg < 4; ++reg) {
        const int qrow = q0H + lg * 4 + reg;
#pragma unroll
        for (int nt = 0; nt < 4; ++nt) {
          const int kv = kv0 + nt * 16 + lr;
          float sv = sH[nt][reg];
          if (km && kv >= vlen) sv -= 1e12f;
          if (kv > qrow) sv -= 1e12f;
          const float p = __expf(sv);
          lH[reg] += p;
          Plds[0][w][lg * 4 + reg][nt * 16 + lr] = f2h(p);
        }
      }
    } else {
#pragma unroll
      for (int reg = 0; reg < 4; ++reg)
#pragma unroll
        for (int nt = 0; nt < 4; ++nt) {
          const float p = __expf(sH[nt][reg]);
          lH[reg] += p;
          Plds[0][w][lg * 4 + reg][nt * 16 + lr] = f2h(p);
        }
    }
    if (lact) {
      if ((t == qtL) | km) {
#pragma unroll
        for (int reg = 0; reg < 4; ++reg) {
          const int qrow = q0L + lg * 4 + reg;
#pragma unroll
          for (int nt = 0; nt < 4; ++nt) {
            const int kv = kv0 + nt * 16 + lr;
            float sv = sL[nt][reg];
            if (km && kv >= vlen) sv -= 1e12f;
            if (kv > qrow) sv -= 1e12f;
            const float p = __expf(sv);
            lL[reg] += p;
            Plds[1][w][lg * 4 + reg][nt * 16 + lr] = f2h(p);
          }
        }
      } else {
#pragma unroll
        for (int reg = 0; reg < 4; ++reg)
#pragma unroll
          for (int nt = 0; nt < 4; ++nt) {
            const float p = __expf(sL[nt][reg]);
            lL[reg] += p;
            Plds[1][w][lg * 4 + reg][nt * 16 + lr] = f2h(p);
          }
      }
    }

#pragma unroll
    for (int c = 0; c < 2; ++c) {
      s16x4 a0 = *(const s16x4*)(&Plds[0][w][lr][c * 32 + lg * 8]);
      s16x4 a1 = *(const s16x4*)(&Plds[0][w][lr][c * 32 + lg * 8 + 4]);
      s16x8 pr = {a0[0], a0[1], a0[2], a0[3], a1[0], a1[1], a1[2], a1[3]};
      f16x8 paH = __builtin_bit_cast(f16x8, pr);
#pragma unroll
      for (int dt = 0; dt < 4; ++dt)
        oH[dt] = __builtin_amdgcn_mfma_f32_16x16x32_f16(paH, vf[dt * 2 + c],
                                                        oH[dt], 0, 0, 0);
    }
    if (lact) {
#pragma unroll
      for (int c = 0; c < 2; ++c) {
        s16x4 a0 = *(const s16x4*)(&Plds[1][w][lr][c * 32 + lg * 8]);
        s16x4 a1 = *(const s16x4*)(&Plds[1][w][lr][c * 32 + lg * 8 + 4]);
        s16x8 pr = {a0[0], a0[1], a0[2], a0[3], a1[0], a1[1], a1[2], a1[3]};
        f16x8 paL = __builtin_bit_cast(f16x8, pr);
#pragma unroll
        for (int dt = 0; dt < 4; ++dt)
          oL[dt] = __builtin_amdgcn_mfma_f32_16x16x32_f16(paL, vf[dt * 2 + c],
                                                          oL[dt], 0, 0, 0);
      }
    }

#pragma unroll
    for (int i = 0; i < 8; ++i) kf[i] = kn[i];
  }

#pragma unroll
  for (int reg = 0; reg < 4; ++reg) {
    float ls = lH[reg];
    ls += __shfl_xor(ls, 1);
    ls += __shfl_xor(ls, 2);
    ls += __shfl_xor(ls, 4);
    ls += __shfl_xor(ls, 8);
    const int qrow = q0H + lg * 4 + reg;
    const float sc = (qrow < qlen) ? (1.f / ls) : 0.f;
#pragma unroll
    for (int dt = 0; dt < 4; ++dt)
      out[(size_t)(b * S_ + qrow) * D_ + h * DH_ + dt * 16 + lr] =
          oH[dt][reg] * sc;
  }
#pragma unroll
  for (int reg = 0; reg < 4; ++reg) {
    float ls = lL[reg];
    ls += __shfl_xor(ls, 1);
    ls += __shfl_xor(ls, 2);
    ls += __shfl_xor(ls, 4);
    ls += __shfl_xor(ls, 8);
    const int qrow = q0L + lg * 4 + reg;
    const float sc = (qrow < qlen) ? (1.f / ls) : 0.f;
#pragma unroll
    for (int dt = 0; dt < 4; ++dt)
      out[(size_t)(b * S_ + qrow) * D_ + h * DH_ + dt * 16 + lr] =
          oL[dt][reg] * sc;
  }
}

// ------------------------------------------------------------------- launch
extern "C" void kernel_launch(void* const* d_in, const int* in_sizes, int n_in,
                              void* d_out, int out_size, void* d_ws,
                              size_t ws_size, hipStream_t stream) {
  const float* Q = (const float*)d_in[0];
  const float* K = (const float*)d_in[1];
  const float* V = (const float*)d_in[2];
  const float* WQ = (const float*)d_in[3];
  const float* WK = (const float*)d_in[4];
  const float* WV = (const float*)d_in[5];
  const int* Qlen = (const int*)d_in[6];
  const int* Vlen = (const int*)d_in[7];
  float* out = (float*)d_out;

  const size_t PE = (size_t)B_ * H_ * S_ * DH_;  // 8388608 elements
  short* qp = (short*)d_ws;
  short* kp = qp + PE;
  short* vT = kp + PE;
  short* wt = vT + PE;  // 3 x 1M fp16 = 6MB (total ws use: 54MB)

  wt_prep<<<dim3(16, 16, 3), dim3(256), 0, stream>>>(WQ, WK, WV, wt);
  proj<0><<<dim3(1024), dim3(256), 0, stream>>>(Q, K, V, wt, qp, kp, vT);
  proj<1><<<dim3(512), dim3(256), 0, stream>>>(Q, K, V, wt, qp, kp, vT);
  attn_fwd<<<dim3(1024), dim3(256), 0, stream>>>(qp, kp, vT, Qlen, Vlen, out);
}

// Round 9
// 168.891 us; speedup vs baseline: 1.2006x; 1.0187x over previous
//
#include <hip/hip_runtime.h>
#include <hip/hip_bf16.h>

// SelfAttention: O = softmax(mask((X_q WQ)(X_k WK)^T/8)) (X_v WV), causal +
// key-padding (V_len) + query (Q_len) masks. B=8 S=1024 D=1024 H=16 Dh=64.
//
// All intermediates FP16. Pipeline:
//   xcvt    : X_{q,k,v} fp32 -> fp16 (streaming; q/k halves use d_out as
//             scratch -- attn fully overwrites d_out afterwards)
//   wt_prep : Wt[3][n][k] = W[k][n] fp16 (transpose+convert)
//   proj    : ONE dispatch, 1536 blocks. slice 0/1: q/k = X @ W; slice 2:
//             vT = Wv^T Xv^T. BOTH operands staged via global_load_lds w16
//             into [2][128][32] double buffers (m97 structure), XOR-granule
//             swizzle on source+read (2-way conflicts = free), 1 barrier/step.
//   attn_fwd: flash attention, shift-free softmax, vlen tile skipping, fused
//             q-tile pairs {15-z, z} per block (K/V tiles loaded once).

#define B_  8
#define S_  1024
#define D_  1024
#define H_  16
#define DH_ 64

using f16x8  = __attribute__((ext_vector_type(8))) _Float16;
using h16x2  = __attribute__((ext_vector_type(2))) __fp16;  // cvt_pkrtz result
using s16x8  = __attribute__((ext_vector_type(8))) short;
using f32x4  = __attribute__((ext_vector_type(4))) float;
using s16x4  = __attribute__((ext_vector_type(4))) short;

__device__ inline short f2h(float x) {
  _Float16 h = (_Float16)x;  // RNE
  return __builtin_bit_cast(short, h);
}

__device__ inline unsigned pk2(float a, float b) {  // 2 fp32 -> packed 2xfp16
  h16x2 p = __builtin_amdgcn_cvt_pkrtz(a, b);
  return __builtin_bit_cast(unsigned, p);
}

__device__ inline f16x8 ld_frag_g(const short* p) {  // 16B aligned
  return __builtin_bit_cast(f16x8, *(const s16x8*)p);
}

#define GLOAD_LDS16(gsrc, ldst)                                              \
  __builtin_amdgcn_global_load_lds(                                          \
      (const __attribute__((address_space(1))) unsigned int*)(gsrc),         \
      (__attribute__((address_space(3))) unsigned int*)(ldst), 16, 0, 0)

// ----------------------------------------------------------------- X convert
// fp32 -> fp16, 4096 floats per block. Coalesced float4 loads / 8B stores.
__global__ __launch_bounds__(256) void xcvt(const float* __restrict__ Qx,
                                            const float* __restrict__ Kx,
                                            const float* __restrict__ Vx,
                                            short* __restrict__ dq,
                                            short* __restrict__ dk,
                                            short* __restrict__ dv) {
  const int slice = blockIdx.y;
  const float* src = (slice == 0) ? Qx : (slice == 1) ? Kx : Vx;
  short* dst = (slice == 0) ? dq : (slice == 1) ? dk : dv;
  const size_t base = (size_t)blockIdx.x * 4096;
  const int tid = threadIdx.x;
#pragma unroll
  for (int j = 0; j < 4; ++j) {
    const size_t off = base + (size_t)(j * 256 + tid) * 4;
    float4 v = *(const float4*)(src + off);
    uint2 u = {pk2(v.x, v.y), pk2(v.z, v.w)};
    *(uint2*)(dst + off) = u;
  }
}

// ------------------------------------------------------------- W transpose
// Wt[slice][n][k] = W_slice[k][n], fp32 -> fp16. 64x64 tiles.
__global__ __launch_bounds__(256) void wt_prep(const float* __restrict__ WQ,
                                               const float* __restrict__ WK,
                                               const float* __restrict__ WV,
                                               short* __restrict__ wt) {
  __shared__ float t[64][65];
  const int slice = blockIdx.z;
  const float* W = (slice == 0) ? WQ : (slice == 1) ? WK : WV;
  const int k0 = blockIdx.y * 64, n0 = blockIdx.x * 64;
  const int tid = threadIdx.x;
  {
    const int r = tid >> 2, c4 = tid & 3;
#pragma unroll
    for (int j = 0; j < 4; ++j) {
      float4 v = *(const float4*)(W + (size_t)(k0 + r) * D_ + n0 + c4 * 16 +
                                  j * 4);
      t[r][c4 * 16 + j * 4 + 0] = v.x;
      t[r][c4 * 16 + j * 4 + 1] = v.y;
      t[r][c4 * 16 + j * 4 + 2] = v.z;
      t[r][c4 * 16 + j * 4 + 3] = v.w;
    }
  }
  __syncthreads();
  {
    const int rn = tid >> 2, ks = tid & 3;
    short* dst =
        wt + ((size_t)slice << 20) + (size_t)(n0 + rn) * D_ + k0 + ks * 16;
    s16x4 h[4];
#pragma unroll
    for (int g = 0; g < 4; ++g)
#pragma unroll
      for (int j = 0; j < 4; ++j) h[g][j] = f2h(t[ks * 16 + g * 4 + j][rn]);
    *(s16x4*)(dst + 0) = h[0];
    *(s16x4*)(dst + 4) = h[1];
    *(s16x4*)(dst + 8) = h[2];
    *(s16x4*)(dst + 12) = h[3];
  }
}

// ---------------------------------------------------------------- projections
// 1536 blocks (3 slices x 512), 256 threads, 128x128 tile, BK=32.
// Both operands fp16 row-major-by-K; staged by global_load_lds width 16 into
// linear [128][32] double buffers. XOR-granule swizzle: slot = g ^ ((row>>1)&3)
// applied on the GLOBAL SOURCE granule and the ds_read granule (involution),
// turning the 8-way row-stride-64B conflict into free 2-way.
__global__ __launch_bounds__(256, 4) void proj(
    const short* __restrict__ xq, const short* __restrict__ xk,
    const short* __restrict__ xv, const short* __restrict__ wt,
    short* __restrict__ qp, short* __restrict__ kp, short* __restrict__ vp) {
  __shared__ __align__(16) short As[2][128][32];
  __shared__ __align__(16) short Bs[2][128][32];
  const int gid = blockIdx.x;
  const int slice = gid >> 9, r = gid & 511;
  const short* A;
  const short* Bp;
  int m0, n0;
  float oscale;
  if (slice < 2) {
    A = slice ? xk : xq;              // rows = tokens (8192)
    Bp = wt + ((size_t)slice << 20);  // rows = H*Dh (1024)
    m0 = (r & 63) * 128;              // m-fast: 64 blocks share one Wt slab
    n0 = (r >> 6) * 128;
    oscale = slice ? 1.0f : 0.125f;
  } else {
    A = wt + ((size_t)2 << 20);  // rows = H*Dh
    Bp = xv;                     // rows = tokens (8192)
    m0 = (r & 7) * 128;          // m-fast: 8 blocks share one X token band
    n0 = (r >> 3) * 128;
    oscale = 1.0f;
  }

  const int tid = threadIdx.x;
  const int lane = tid & 63, w = tid >> 6;
  const int wr = w >> 1, wc = w & 1;
  const int lr = lane & 15, lg = lane >> 4;
  const int g_row = tid >> 2, g_c = tid & 3;
  const int gsw = (g_c ^ ((g_row >> 1) & 3)) * 8;  // swizzled src granule
  const int rsw = (lg ^ ((lr >> 1) & 3)) * 8;      // swizzled read granule

  const short* ga = A + (size_t)(m0 + g_row) * D_ + gsw;
  const short* gb = Bp + (size_t)(n0 + g_row) * D_ + gsw;

  f32x4 acc[4][4];
#pragma unroll
  for (int i = 0; i < 4; ++i)
#pragma unroll
    for (int j = 0; j < 4; ++j) acc[i][j] = f32x4{0.f, 0.f, 0.f, 0.f};

  // prologue: stage step 0
  GLOAD_LDS16(ga, &As[0][g_row][g_c * 8]);
  GLOAD_LDS16(ga + (size_t)64 * D_, &As[0][g_row + 64][g_c * 8]);
  GLOAD_LDS16(gb, &Bs[0][g_row][g_c * 8]);
  GLOAD_LDS16(gb + (size_t)64 * D_, &Bs[0][g_row + 64][g_c * 8]);
  __syncthreads();

  for (int kt = 0; kt < 32; ++kt) {
    const int cur = kt & 1, nxt = cur ^ 1;
    if (kt < 31) {
      const int k1 = (kt + 1) * 32;
      GLOAD_LDS16(ga + k1, &As[nxt][g_row][g_c * 8]);
      GLOAD_LDS16(ga + (size_t)64 * D_ + k1, &As[nxt][g_row + 64][g_c * 8]);
      GLOAD_LDS16(gb + k1, &Bs[nxt][g_row][g_c * 8]);
      GLOAD_LDS16(gb + (size_t)64 * D_ + k1, &Bs[nxt][g_row + 64][g_c * 8]);
    }

    f16x8 af[4], bf[4];
#pragma unroll
    for (int mi = 0; mi < 4; ++mi)
      af[mi] = ld_frag_g(&As[cur][wr * 64 + mi * 16 + lr][rsw]);
#pragma unroll
    for (int ni = 0; ni < 4; ++ni)
      bf[ni] = ld_frag_g(&Bs[cur][wc * 64 + ni * 16 + lr][rsw]);
#pragma unroll
    for (int mi = 0; mi < 4; ++mi)
#pragma unroll
      for (int ni = 0; ni < 4; ++ni)
        acc[mi][ni] = __builtin_amdgcn_mfma_f32_16x16x32_f16(
            af[mi], bf[ni], acc[mi][ni], 0, 0, 0);
    __syncthreads();  // drains next-buffer gloads; all waves done with cur
  }

  // epilogue
  short* outp = (slice == 0) ? qp : kp;
#pragma unroll
  for (int mi = 0; mi < 4; ++mi)
#pragma unroll
    for (int ni = 0; ni < 4; ++ni) {
      const int mg0 = m0 + wr * 64 + mi * 16 + lg * 4;
      const int ng = n0 + wc * 64 + ni * 16 + lr;
#pragma unroll
      for (int reg = 0; reg < 4; ++reg) {
        const int m = mg0 + reg;
        const short val = f2h(acc[mi][ni][reg] * oscale);
        if (slice < 2) {
          const int b = m >> 10, s = m & 1023, hh = ng >> 6, dh = ng & 63;
          outp[((size_t)((b * H_ + hh) * S_) + s) * DH_ + dh] = val;
        } else {
          vp[((size_t)(ng >> 10) << 20) + (size_t)m * S_ + (ng & 1023)] = val;
        }
      }
    }
}

// ----------------------------------------------------------------- attention
// Block = (b, h, z): q-tiles {qtH=15-z, qtL=z}, ONE fused sweep over KV tiles;
// shared K/V tiles loaded once feed both halves' QK^T and PV MFMAs.
// Shift-free softmax (p = exp(s); exp(s - 1e12) == 0.0f exactly). Tiles with
// kv0 >= vlen skipped (vlen>0); vlen==0 degrades to plain causal softmax.
__global__ __launch_bounds__(256, 2) void attn_fwd(
    const short* __restrict__ qp, const short* __restrict__ kp,
    const short* __restrict__ vT, const int* __restrict__ Qlen,
    const int* __restrict__ Vlen, float* __restrict__ out) {
  __shared__ short Plds[2][4][16][72];
  const int bid = blockIdx.x;
  const int z = bid & 7;
  const int bh = bid >> 3;
  const int h = bh & 15;
  const int b = bh >> 4;
  const int lane = threadIdx.x & 63;
  const int w = threadIdx.x >> 6;
  const int lr = lane & 15, lg = lane >> 4;
  const short* qb = qp + (size_t)((b * H_ + h) * S_) * DH_;
  const short* kb = kp + (size_t)((b * H_ + h) * S_) * DH_;
  const short* vb = vT + (size_t)((b * H_ + h) * DH_) * S_;
  const int vlen = Vlen[b], qlen = Qlen[b];

  const int qtH = 15 - z, qtL = z;
  const int vcap = (vlen + 63) >> 6;
  const int nTH = (vlen > 0) ? min(qtH + 1, vcap) : (qtH + 1);
  const int nTL = (vlen > 0) ? min(qtL + 1, vcap) : (qtL + 1);
  const int q0H = qtH * 64 + w * 16;
  const int q0L = qtL * 64 + w * 16;

  f16x8 qfH[2], qfL[2];
#pragma unroll
  for (int c = 0; c < 2; ++c) {
    qfH[c] = ld_frag_g(qb + (size_t)(q0H + lr) * DH_ + c * 32 + lg * 8);
    qfL[c] = ld_frag_g(qb + (size_t)(q0L + lr) * DH_ + c * 32 + lg * 8);
  }

  float lH[4], lL[4];
  f32x4 oH[4], oL[4];
#pragma unroll
  for (int rr = 0; rr < 4; ++rr) {
    lH[rr] = 0.f; lL[rr] = 0.f;
    oH[rr] = f32x4{0.f, 0.f, 0.f, 0.f};
    oL[rr] = f32x4{0.f, 0.f, 0.f, 0.f};
  }

  f16x8 kf[8];
#pragma unroll
  for (int nt = 0; nt < 4; ++nt)
#pragma unroll
    for (int c = 0; c < 2; ++c)
      kf[nt * 2 + c] =
          ld_frag_g(kb + (size_t)(nt * 16 + lr) * DH_ + c * 32 + lg * 8);

  for (int t = 0; t < nTH; ++t) {
    const int kv0 = t * 64;
    const int kvn = (t + 1 < nTH) ? kv0 + 64 : kv0;
    const bool lact = t < nTL;

    f16x8 vf[8];
#pragma unroll
    for (int dt = 0; dt < 4; ++dt)
#pragma unroll
      for (int c = 0; c < 2; ++c)
        vf[dt * 2 + c] =
            ld_frag_g(vb + (size_t)(dt * 16 + lr) * S_ + kv0 + c * 32 + lg * 8);

    f16x8 kn[8];
#pragma unroll
    for (int nt = 0; nt < 4; ++nt)
#pragma unroll
      for (int c = 0; c < 2; ++c)
        kn[nt * 2 + c] = ld_frag_g(kb + (size_t)(kvn + nt * 16 + lr) * DH_ +
                                   c * 32 + lg * 8);

    f32x4 sH[4], sL[4];
#pragma unroll
    for (int nt = 0; nt < 4; ++nt) sH[nt] = f32x4{0.f, 0.f, 0.f, 0.f};
#pragma unroll
    for (int nt = 0; nt < 4; ++nt)
#pragma unroll
      for (int c = 0; c < 2; ++c)
        sH[nt] = __builtin_amdgcn_mfma_f32_16x16x32_f16(qfH[c], kf[nt * 2 + c],
                                                        sH[nt], 0, 0, 0);
    if (lact) {
#pragma unroll
      for (int nt = 0; nt < 4; ++nt) sL[nt] = f32x4{0.f, 0.f, 0.f, 0.f};
#pragma unroll
      for (int nt = 0; nt < 4; ++nt)
#pragma unroll
        for (int c = 0; c < 2; ++c)
          sL[nt] = __builtin_amdgcn_mfma_f32_16x16x32_f16(
              qfL[c], kf[nt * 2 + c], sL[nt], 0, 0, 0);
    }

    const bool km = (vlen > 0) && (vlen - kv0 < 64);

    if ((t == qtH) | km) {
#pragma unroll
      for (int reg = 0; reg < 4; ++reg) {
        const int qrow = q0H + lg * 4 + reg;
#pragma unroll
        for (int nt = 0; nt < 4; ++nt) {
          const int kv = kv0 + nt * 16 + lr;
          float sv = sH[nt][reg];
          if (km && kv >= vlen) sv -= 1e12f;
          if (kv > qrow) sv -= 1e12f;
          const float p = __expf(sv);
          lH[reg] += p;
          Plds[0][w][lg * 4 + reg][nt * 16 + lr] = f2h(p);
        }
      }
    } else {
#pragma unroll
      for (int reg = 0; reg < 4; ++reg)
#pragma unroll
        for (int nt = 0; nt < 4; ++nt) {
          const float p = __expf(sH[nt][reg]);
          lH[reg] += p;
          Plds[0][w][lg * 4 + reg][nt * 16 + lr] = f2h(p);
        }
    }
    if (lact) {
      if ((t == qtL) | km) {
#pragma unroll
        for (int reg = 0; reg < 4; ++reg) {
          const int qrow = q0L + lg * 4 + reg;
#pragma unroll
          for (int nt = 0; nt < 4; ++nt) {
            const int kv = kv0 + nt * 16 + lr;
            float sv = sL[nt][reg];
            if (km && kv >= vlen) sv -= 1e12f;
            if (kv > qrow) sv -= 1e12f;
            const float p = __expf(sv);
            lL[reg] += p;
            Plds[1][w][lg * 4 + reg][nt * 16 + lr] = f2h(p);
          }
        }
      } else {
#pragma unroll
        for (int reg = 0; reg < 4; ++reg)
#pragma unroll
          for (int nt = 0; nt < 4; ++nt) {
            const float p = __expf(sL[nt][reg]);
            lL[reg] += p;
            Plds[1][w][lg * 4 + reg][nt * 16 + lr] = f2h(p);
          }
      }
    }

#pragma unroll
    for (int c = 0; c < 2; ++c) {
      s16x4 a0 = *(const s16x4*)(&Plds[0][w][lr][c * 32 + lg * 8]);
      s16x4 a1 = *(const s16x4*)(&Plds[0][w][lr][c * 32 + lg * 8 + 4]);
      s16x8 pr = {a0[0], a0[1], a0[2], a0[3], a1[0], a1[1], a1[2], a1[3]};
      f16x8 paH = __builtin_bit_cast(f16x8, pr);
#pragma unroll
      for (int dt = 0; dt < 4; ++dt)
        oH[dt] = __builtin_amdgcn_mfma_f32_16x16x32_f16(paH, vf[dt * 2 + c],
                                                        oH[dt], 0, 0, 0);
    }
    if (lact) {
#pragma unroll
      for (int c = 0; c < 2; ++c) {
        s16x4 a0 = *(const s16x4*)(&Plds[1][w][lr][c * 32 + lg * 8]);
        s16x4 a1 = *(const s16x4*)(&Plds[1][w][lr][c * 32 + lg * 8 + 4]);
        s16x8 pr = {a0[0], a0[1], a0[2], a0[3], a1[0], a1[1], a1[2], a1[3]};
        f16x8 paL = __builtin_bit_cast(f16x8, pr);
#pragma unroll
        for (int dt = 0; dt < 4; ++dt)
          oL[dt] = __builtin_amdgcn_mfma_f32_16x16x32_f16(paL, vf[dt * 2 + c],
                                                          oL[dt], 0, 0, 0);
      }
    }

#pragma unroll
    for (int i = 0; i < 8; ++i) kf[i] = kn[i];
  }

#pragma unroll
  for (int reg = 0; reg < 4; ++reg) {
    float ls = lH[reg];
    ls += __shfl_xor(ls, 1);
    ls += __shfl_xor(ls, 2);
    ls += __shfl_xor(ls, 4);
    ls += __shfl_xor(ls, 8);
    const int qrow = q0H + lg * 4 + reg;
    const float sc = (qrow < qlen) ? (1.f / ls) : 0.f;
#pragma unroll
    for (int dt = 0; dt < 4; ++dt)
      out[(size_t)(b * S_ + qrow) * D_ + h * DH_ + dt * 16 + lr] =
          oH[dt][reg] * sc;
  }
#pragma unroll
  for (int reg = 0; reg < 4; ++reg) {
    float ls = lL[reg];
    ls += __shfl_xor(ls, 1);
    ls += __shfl_xor(ls, 2);
    ls += __shfl_xor(ls, 4);
    ls += __shfl_xor(ls, 8);
    const int qrow = q0L + lg * 4 + reg;
    const float sc = (qrow < qlen) ? (1.f / ls) : 0.f;
#pragma unroll
    for (int dt = 0; dt < 4; ++dt)
      out[(size_t)(b * S_ + qrow) * D_ + h * DH_ + dt * 16 + lr] =
          oL[dt][reg] * sc;
  }
}

// ------------------------------------------------------------------- launch
extern "C" void kernel_launch(void* const* d_in, const int* in_sizes, int n_in,
                              void* d_out, int out_size, void* d_ws,
                              size_t ws_size, hipStream_t stream) {
  const float* Q = (const float*)d_in[0];
  const float* K = (const float*)d_in[1];
  const float* V = (const float*)d_in[2];
  const float* WQ = (const float*)d_in[3];
  const float* WK = (const float*)d_in[4];
  const float* WV = (const float*)d_in[5];
  const int* Qlen = (const int*)d_in[6];
  const int* Vlen = (const int*)d_in[7];
  float* out = (float*)d_out;

  const size_t PE = (size_t)B_ * H_ * S_ * DH_;  // 8388608 elements
  short* qp = (short*)d_ws;
  short* kp = qp + PE;
  short* vT = kp + PE;
  short* wt = vT + PE;            // 3 x 1M fp16 = 6MB
  short* xhV = wt + 3 * 1048576;  // 16MB (ws total 70MB)
  // Q/K fp16 scratch lives in d_out (33.5MB >= 32MB); attn_fwd fully
  // overwrites d_out afterwards, so this is deterministic & safe.
  short* xhQ = (short*)d_out;
  short* xhK = xhQ + PE;

  xcvt<<<dim3(2048, 3), dim3(256), 0, stream>>>(Q, K, V, xhQ, xhK, xhV);
  wt_prep<<<dim3(16, 16, 3), dim3(256), 0, stream>>>(WQ, WK, WV, wt);
  proj<<<dim3(1536), dim3(256), 0, stream>>>(xhQ, xhK, xhV, wt, qp, kp, vT);
  attn_fwd<<<dim3(1024), dim3(256), 0, stream>>>(qp, kp, vT, Qlen, Vlen, out);
}

// Round 10
// 163.334 us; speedup vs baseline: 1.2415x; 1.0340x over previous
//
#include <hip/hip_runtime.h>
#include <hip/hip_bf16.h>

// SelfAttention: O = softmax(mask((X_q WQ)(X_k WK)^T/8)) (X_v WV), causal +
// key-padding (V_len) + query (Q_len) masks. B=8 S=1024 D=1024 H=16 Dh=64.
//
// All intermediates FP16. Pipeline:
//   prep    : (merged) X fp32->fp16 streams + Wt[3][n][k] transpose
//   proj    : ONE dispatch, 1536 blocks; 128^2 tile, BK=32; both operands via
//             global_load_lds w16 into THREE rotating LDS buffers; counted
//             s_waitcnt vmcnt(4) + raw s_barrier per step (loads for t+1/t+2
//             stay in flight ACROSS the barrier -- no vmcnt(0) drain);
//             XOR-granule swizzle on source+read (conflict-free ds_read_b128).
//   attn_fwd: flash attention, shift-free softmax, vlen tile skipping, fused
//             q-tile pairs {15-z, z} per block (K/V tiles loaded once).

#define B_  8
#define S_  1024
#define D_  1024
#define H_  16
#define DH_ 64

using f16x8  = __attribute__((ext_vector_type(8))) _Float16;
using h16x2  = __attribute__((ext_vector_type(2))) __fp16;  // cvt_pkrtz result
using s16x8  = __attribute__((ext_vector_type(8))) short;
using f32x4  = __attribute__((ext_vector_type(4))) float;
using s16x4  = __attribute__((ext_vector_type(4))) short;

__device__ inline short f2h(float x) {
  _Float16 h = (_Float16)x;  // RNE
  return __builtin_bit_cast(short, h);
}

__device__ inline unsigned pk2(float a, float b) {  // 2 fp32 -> packed 2xfp16
  h16x2 p = __builtin_amdgcn_cvt_pkrtz(a, b);
  return __builtin_bit_cast(unsigned, p);
}

__device__ inline f16x8 ld_frag_g(const short* p) {  // 16B aligned
  return __builtin_bit_cast(f16x8, *(const s16x8*)p);
}

#define GLOAD_LDS16(gsrc, ldst)                                              \
  __builtin_amdgcn_global_load_lds(                                          \
      (const __attribute__((address_space(1))) unsigned int*)(gsrc),         \
      (__attribute__((address_space(3))) unsigned int*)(ldst), 16, 0, 0)

// -------------------------------------------------------------------- prep
// blocks 0..6143  : xcvt  (slice = bid>>11, 4096 floats per block)
// blocks 6144..6911: wt_prep (Wt[slice][n][k] = W[k][n], 64x64 tiles)
__global__ __launch_bounds__(256) void prep(
    const float* __restrict__ Qx, const float* __restrict__ Kx,
    const float* __restrict__ Vx, const float* __restrict__ WQ,
    const float* __restrict__ WK, const float* __restrict__ WV,
    short* __restrict__ dq, short* __restrict__ dk, short* __restrict__ dv,
    short* __restrict__ wt) {
  __shared__ float t[64][65];
  const int bid = blockIdx.x;
  const int tid = threadIdx.x;
  if (bid < 6144) {
    const int slice = bid >> 11;
    const float* src = (slice == 0) ? Qx : (slice == 1) ? Kx : Vx;
    short* dst = (slice == 0) ? dq : (slice == 1) ? dk : dv;
    const size_t base = (size_t)(bid & 2047) * 4096;
#pragma unroll
    for (int j = 0; j < 4; ++j) {
      const size_t off = base + (size_t)(j * 256 + tid) * 4;
      float4 v = *(const float4*)(src + off);
      uint2 u = {pk2(v.x, v.y), pk2(v.z, v.w)};
      *(uint2*)(dst + off) = u;
    }
  } else {
    const int wid = bid - 6144;
    const int slice = wid >> 8;
    const int rem = wid & 255;
    const int n0 = (rem & 15) * 64, k0 = (rem >> 4) * 64;
    const float* W = (slice == 0) ? WQ : (slice == 1) ? WK : WV;
    {
      const int r = tid >> 2, c4 = tid & 3;
#pragma unroll
      for (int j = 0; j < 4; ++j) {
        float4 v = *(const float4*)(W + (size_t)(k0 + r) * D_ + n0 + c4 * 16 +
                                    j * 4);
        t[r][c4 * 16 + j * 4 + 0] = v.x;
        t[r][c4 * 16 + j * 4 + 1] = v.y;
        t[r][c4 * 16 + j * 4 + 2] = v.z;
        t[r][c4 * 16 + j * 4 + 3] = v.w;
      }
    }
    __syncthreads();
    {
      const int rn = tid >> 2, ks = tid & 3;
      short* dst =
          wt + ((size_t)slice << 20) + (size_t)(n0 + rn) * D_ + k0 + ks * 16;
      s16x4 h[4];
#pragma unroll
      for (int g = 0; g < 4; ++g)
#pragma unroll
        for (int j = 0; j < 4; ++j) h[g][j] = f2h(t[ks * 16 + g * 4 + j][rn]);
      *(s16x4*)(dst + 0) = h[0];
      *(s16x4*)(dst + 4) = h[1];
      *(s16x4*)(dst + 8) = h[2];
      *(s16x4*)(dst + 12) = h[3];
    }
  }
}

// ---------------------------------------------------------------- projections
// 1536 blocks (3 slices x 512), 256 threads, 128x128 tile, BK=32.
// THREE rotating [128][32] buffers per operand; stage depth 2; per step:
//   s_waitcnt vmcnt(4)  (oldest 4 loads = buf[t] landed; 8 outstanding)
//   s_barrier           (all waves' buf[t] contributions landed)
//   stage buf[t+2]      (4 global_load_lds w16; stays in flight across bar)
//   ds_read(swz) + 16 MFMA on buf[t]
// XOR-granule swizzle (src+read involution) keeps ds_read_b128 conflict-free.
__global__ __launch_bounds__(256, 3) void proj(
    const short* __restrict__ xq, const short* __restrict__ xk,
    const short* __restrict__ xv, const short* __restrict__ wt,
    short* __restrict__ qp, short* __restrict__ kp, short* __restrict__ vp) {
  __shared__ __align__(16) short As[3][128][32];
  __shared__ __align__(16) short Bs[3][128][32];
  const int gid = blockIdx.x;
  const int slice = gid >> 9, r = gid & 511;
  const short* A;
  const short* Bp;
  int m0, n0;
  float oscale;
  if (slice < 2) {
    A = slice ? xk : xq;              // rows = tokens (8192)
    Bp = wt + ((size_t)slice << 20);  // rows = H*Dh (1024)
    m0 = (r & 63) * 128;              // m-fast: 64 blocks share one Wt slab
    n0 = (r >> 6) * 128;
    oscale = slice ? 1.0f : 0.125f;
  } else {
    A = wt + ((size_t)2 << 20);  // rows = H*Dh
    Bp = xv;                     // rows = tokens (8192)
    m0 = (r & 7) * 128;          // m-fast: 8 blocks share one X token band
    n0 = (r >> 3) * 128;
    oscale = 1.0f;
  }

  const int tid = threadIdx.x;
  const int lane = tid & 63, w = tid >> 6;
  const int wr = w >> 1, wc = w & 1;
  const int lr = lane & 15, lg = lane >> 4;
  const int g_row = tid >> 2, g_c = tid & 3;
  const int gsw = (g_c ^ ((g_row >> 1) & 3)) * 8;  // swizzled src granule
  const int rsw = (lg ^ ((lr >> 1) & 3)) * 8;      // swizzled read granule

  const short* ga = A + (size_t)(m0 + g_row) * D_ + gsw;
  const short* gb = Bp + (size_t)(n0 + g_row) * D_ + gsw;

  f32x4 acc[4][4];
#pragma unroll
  for (int i = 0; i < 4; ++i)
#pragma unroll
    for (int j = 0; j < 4; ++j) acc[i][j] = f32x4{0.f, 0.f, 0.f, 0.f};

  // prologue: stage buf0 (kt=0) and buf1 (kt=1); 8 loads outstanding
  GLOAD_LDS16(ga, &As[0][g_row][g_c * 8]);
  GLOAD_LDS16(ga + (size_t)64 * D_, &As[0][g_row + 64][g_c * 8]);
  GLOAD_LDS16(gb, &Bs[0][g_row][g_c * 8]);
  GLOAD_LDS16(gb + (size_t)64 * D_, &Bs[0][g_row + 64][g_c * 8]);
  GLOAD_LDS16(ga + 32, &As[1][g_row][g_c * 8]);
  GLOAD_LDS16(ga + (size_t)64 * D_ + 32, &As[1][g_row + 64][g_c * 8]);
  GLOAD_LDS16(gb + 32, &Bs[1][g_row][g_c * 8]);
  GLOAD_LDS16(gb + (size_t)64 * D_ + 32, &Bs[1][g_row + 64][g_c * 8]);

  for (int kt = 0; kt < 32; ++kt) {
    const int cur = kt % 3;
    if (kt < 30)
      asm volatile("s_waitcnt vmcnt(4)" ::: "memory");
    else
      asm volatile("s_waitcnt vmcnt(0)" ::: "memory");
    __builtin_amdgcn_s_barrier();
    __builtin_amdgcn_sched_barrier(0);
    if (kt < 30) {
      const int pre = (kt + 2) % 3;
      const int k2 = (kt + 2) * 32;
      GLOAD_LDS16(ga + k2, &As[pre][g_row][g_c * 8]);
      GLOAD_LDS16(ga + (size_t)64 * D_ + k2, &As[pre][g_row + 64][g_c * 8]);
      GLOAD_LDS16(gb + k2, &Bs[pre][g_row][g_c * 8]);
      GLOAD_LDS16(gb + (size_t)64 * D_ + k2, &Bs[pre][g_row + 64][g_c * 8]);
    }

    f16x8 af[4], bf[4];
#pragma unroll
    for (int mi = 0; mi < 4; ++mi)
      af[mi] = ld_frag_g(&As[cur][wr * 64 + mi * 16 + lr][rsw]);
#pragma unroll
    for (int ni = 0; ni < 4; ++ni)
      bf[ni] = ld_frag_g(&Bs[cur][wc * 64 + ni * 16 + lr][rsw]);
#pragma unroll
    for (int mi = 0; mi < 4; ++mi)
#pragma unroll
      for (int ni = 0; ni < 4; ++ni)
        acc[mi][ni] = __builtin_amdgcn_mfma_f32_16x16x32_f16(
            af[mi], bf[ni], acc[mi][ni], 0, 0, 0);
  }

  // epilogue
  short* outp = (slice == 0) ? qp : kp;
#pragma unroll
  for (int mi = 0; mi < 4; ++mi)
#pragma unroll
    for (int ni = 0; ni < 4; ++ni) {
      const int mg0 = m0 + wr * 64 + mi * 16 + lg * 4;
      const int ng = n0 + wc * 64 + ni * 16 + lr;
#pragma unroll
      for (int reg = 0; reg < 4; ++reg) {
        const int m = mg0 + reg;
        const short val = f2h(acc[mi][ni][reg] * oscale);
        if (slice < 2) {
          const int b = m >> 10, s = m & 1023, hh = ng >> 6, dh = ng & 63;
          outp[((size_t)((b * H_ + hh) * S_) + s) * DH_ + dh] = val;
        } else {
          vp[((size_t)(ng >> 10) << 20) + (size_t)m * S_ + (ng & 1023)] = val;
        }
      }
    }
}

// ----------------------------------------------------------------- attention
// Block = (b, h, z): q-tiles {qtH=15-z, qtL=z}, ONE fused sweep over KV tiles;
// shared K/V tiles loaded once feed both halves' QK^T and PV MFMAs.
// Shift-free softmax (p = exp(s); exp(s - 1e12) == 0.0f exactly). Tiles with
// kv0 >= vlen skipped (vlen>0); vlen==0 degrades to plain causal softmax.
__global__ __launch_bounds__(256, 2) void attn_fwd(
    const short* __restrict__ qp, const short* __restrict__ kp,
    const short* __restrict__ vT, const int* __restrict__ Qlen,
    const int* __restrict__ Vlen, float* __restrict__ out) {
  __shared__ short Plds[2][4][16][72];
  const int bid = blockIdx.x;
  const int z = bid & 7;
  const int bh = bid >> 3;
  const int h = bh & 15;
  const int b = bh >> 4;
  const int lane = threadIdx.x & 63;
  const int w = threadIdx.x >> 6;
  const int lr = lane & 15, lg = lane >> 4;
  const short* qb = qp + (size_t)((b * H_ + h) * S_) * DH_;
  const short* kb = kp + (size_t)((b * H_ + h) * S_) * DH_;
  const short* vb = vT + (size_t)((b * H_ + h) * DH_) * S_;
  const int vlen = Vlen[b], qlen = Qlen[b];

  const int qtH = 15 - z, qtL = z;
  const int vcap = (vlen + 63) >> 6;
  const int nTH = (vlen > 0) ? min(qtH + 1, vcap) : (qtH + 1);
  const int nTL = (vlen > 0) ? min(qtL + 1, vcap) : (qtL + 1);
  const int q0H = qtH * 64 + w * 16;
  const int q0L = qtL * 64 + w * 16;

  f16x8 qfH[2], qfL[2];
#pragma unroll
  for (int c = 0; c < 2; ++c) {
    qfH[c] = ld_frag_g(qb + (size_t)(q0H + lr) * DH_ + c * 32 + lg * 8);
    qfL[c] = ld_frag_g(qb + (size_t)(q0L + lr) * DH_ + c * 32 + lg * 8);
  }

  float lH[4], lL[4];
  f32x4 oH[4], oL[4];
#pragma unroll
  for (int rr = 0; rr < 4; ++rr) {
    lH[rr] = 0.f; lL[rr] = 0.f;
    oH[rr] = f32x4{0.f, 0.f, 0.f, 0.f};
    oL[rr] = f32x4{0.f, 0.f, 0.f, 0.f};
  }

  f16x8 kf[8];
#pragma unroll
  for (int nt = 0; nt < 4; ++nt)
#pragma unroll
    for (int c = 0; c < 2; ++c)
      kf[nt * 2 + c] =
          ld_frag_g(kb + (size_t)(nt * 16 + lr) * DH_ + c * 32 + lg * 8);

  for (int t = 0; t < nTH; ++t) {
    const int kv0 = t * 64;
    const int kvn = (t + 1 < nTH) ? kv0 + 64 : kv0;
    const bool lact = t < nTL;

    f16x8 vf[8];
#pragma unroll
    for (int dt = 0; dt < 4; ++dt)
#pragma unroll
      for (int c = 0; c < 2; ++c)
        vf[dt * 2 + c] =
            ld_frag_g(vb + (size_t)(dt * 16 + lr) * S_ + kv0 + c * 32 + lg * 8);

    f16x8 kn[8];
#pragma unroll
    for (int nt = 0; nt < 4; ++nt)
#pragma unroll
      for (int c = 0; c < 2; ++c)
        kn[nt * 2 + c] = ld_frag_g(kb + (size_t)(kvn + nt * 16 + lr) * DH_ +
                                   c * 32 + lg * 8);

    f32x4 sH[4], sL[4];
#pragma unroll
    for (int nt = 0; nt < 4; ++nt) sH[nt] = f32x4{0.f, 0.f, 0.f, 0.f};
#pragma unroll
    for (int nt = 0; nt < 4; ++nt)
#pragma unroll
      for (int c = 0; c < 2; ++c)
        sH[nt] = __builtin_amdgcn_mfma_f32_16x16x32_f16(qfH[c], kf[nt * 2 + c],
                                                        sH[nt], 0, 0, 0);
    if (lact) {
#pragma unroll
      for (int nt = 0; nt < 4; ++nt) sL[nt] = f32x4{0.f, 0.f, 0.f, 0.f};
#pragma unroll
      for (int nt = 0; nt < 4; ++nt)
#pragma unroll
        for (int c = 0; c < 2; ++c)
          sL[nt] = __builtin_amdgcn_mfma_f32_16x16x32_f16(
              qfL[c], kf[nt * 2 + c], sL[nt], 0, 0, 0);
    }

    const bool km = (vlen > 0) && (vlen - kv0 < 64);

    if ((t == qtH) | km) {
#pragma unroll
      for (int reg = 0; reg < 4; ++reg) {
        const int qrow = q0H + lg * 4 + reg;
#pragma unroll
        for (int nt = 0; nt < 4; ++nt) {
          const int kv = kv0 + nt * 16 + lr;
          float sv = sH[nt][reg];
          if (km && kv >= vlen) sv -= 1e12f;
          if (kv > qrow) sv -= 1e12f;
          const float p = __expf(sv);
          lH[reg] += p;
          Plds[0][w][lg * 4 + reg][nt * 16 + lr] = f2h(p);
        }
      }
    } else {
#pragma unroll
      for (int reg = 0; reg < 4; ++reg)
#pragma unroll
        for (int nt = 0; nt < 4; ++nt) {
          const float p = __expf(sH[nt][reg]);
          lH[reg] += p;
          Plds[0][w][lg * 4 + reg][nt * 16 + lr] = f2h(p);
        }
    }
    if (lact) {
      if ((t == qtL) | km) {
#pragma unroll
        for (int reg = 0; reg < 4; ++reg) {
          const int qrow = q0L + lg * 4 + reg;
#pragma unroll
          for (int nt = 0; nt < 4; ++nt) {
            const int kv = kv0 + nt * 16 + lr;
            float sv = sL[nt][reg];
            if (km && kv >= vlen) sv -= 1e12f;
            if (kv > qrow) sv -= 1e12f;
            const float p = __expf(sv);
            lL[reg] += p;
            Plds[1][w][lg * 4 + reg][nt * 16 + lr] = f2h(p);
          }
        }
      } else {
#pragma unroll
        for (int reg = 0; reg < 4; ++reg)
#pragma unroll
          for (int nt = 0; nt < 4; ++nt) {
            const float p = __expf(sL[nt][reg]);
            lL[reg] += p;
            Plds[1][w][lg * 4 + reg][nt * 16 + lr] = f2h(p);
          }
      }
    }

#pragma unroll
    for (int c = 0; c < 2; ++c) {
      s16x4 a0 = *(const s16x4*)(&Plds[0][w][lr][c * 32 + lg * 8]);
      s16x4 a1 = *(const s16x4*)(&Plds[0][w][lr][c * 32 + lg * 8 + 4]);
      s16x8 pr = {a0[0], a0[1], a0[2], a0[3], a1[0], a1[1], a1[2], a1[3]};
      f16x8 paH = __builtin_bit_cast(f16x8, pr);
#pragma unroll
      for (int dt = 0; dt < 4; ++dt)
        oH[dt] = __builtin_amdgcn_mfma_f32_16x16x32_f16(paH, vf[dt * 2 + c],
                                                        oH[dt], 0, 0, 0);
    }
    if (lact) {
#pragma unroll
      for (int c = 0; c < 2; ++c) {
        s16x4 a0 = *(const s16x4*)(&Plds[1][w][lr][c * 32 + lg * 8]);
        s16x4 a1 = *(const s16x4*)(&Plds[1][w][lr][c * 32 + lg * 8 + 4]);
        s16x8 pr = {a0[0], a0[1], a0[2], a0[3], a1[0], a1[1], a1[2], a1[3]};
        f16x8 paL = __builtin_bit_cast(f16x8, pr);
#pragma unroll
        for (int dt = 0; dt < 4; ++dt)
          oL[dt] = __builtin_amdgcn_mfma_f32_16x16x32_f16(paL, vf[dt * 2 + c],
                                                          oL[dt], 0, 0, 0);
      }
    }

#pragma unroll
    for (int i = 0; i < 8; ++i) kf[i] = kn[i];
  }

#pragma unroll
  for (int reg = 0; reg < 4; ++reg) {
    float ls = lH[reg];
    ls += __shfl_xor(ls, 1);
    ls += __shfl_xor(ls, 2);
    ls += __shfl_xor(ls, 4);
    ls += __shfl_xor(ls, 8);
    const int qrow = q0H + lg * 4 + reg;
    const float sc = (qrow < qlen) ? (1.f / ls) : 0.f;
#pragma unroll
    for (int dt = 0; dt < 4; ++dt)
      out[(size_t)(b * S_ + qrow) * D_ + h * DH_ + dt * 16 + lr] =
          oH[dt][reg] * sc;
  }
#pragma unroll
  for (int reg = 0; reg < 4; ++reg) {
    float ls = lL[reg];
    ls += __shfl_xor(ls, 1);
    ls += __shfl_xor(ls, 2);
    ls += __shfl_xor(ls, 4);
    ls += __shfl_xor(ls, 8);
    const int qrow = q0L + lg * 4 + reg;
    const float sc = (qrow < qlen) ? (1.f / ls) : 0.f;
#pragma unroll
    for (int dt = 0; dt < 4; ++dt)
      out[(size_t)(b * S_ + qrow) * D_ + h * DH_ + dt * 16 + lr] =
          oL[dt][reg] * sc;
  }
}

// ------------------------------------------------------------------- launch
extern "C" void kernel_launch(void* const* d_in, const int* in_sizes, int n_in,
                              void* d_out, int out_size, void* d_ws,
                              size_t ws_size, hipStream_t stream) {
  const float* Q = (const float*)d_in[0];
  const float* K = (const float*)d_in[1];
  const float* V = (const float*)d_in[2];
  const float* WQ = (const float*)d_in[3];
  const float* WK = (const float*)d_in[4];
  const float* WV = (const float*)d_in[5];
  const int* Qlen = (const int*)d_in[6];
  const int* Vlen = (const int*)d_in[7];
  float* out = (float*)d_out;

  const size_t PE = (size_t)B_ * H_ * S_ * DH_;  // 8388608 elements
  short* qp = (short*)d_ws;
  short* kp = qp + PE;
  short* vT = kp + PE;
  short* wt = vT + PE;            // 3 x 1M fp16 = 6MB
  short* xhV = wt + 3 * 1048576;  // 16MB (ws total 70MB)
  // Q/K fp16 scratch lives in d_out (33.5MB >= 32MB); attn_fwd fully
  // overwrites d_out afterwards, so this is deterministic & safe.
  short* xhQ = (short*)d_out;
  short* xhK = xhQ + PE;

  prep<<<dim3(6912), dim3(256), 0, stream>>>(Q, K, V, WQ, WK, WV, xhQ, xhK,
                                             xhV, wt);
  proj<<<dim3(1536), dim3(256), 0, stream>>>(xhQ, xhK, xhV, wt, qp, kp, vT);
  attn_fwd<<<dim3(1024), dim3(256), 0, stream>>>(qp, kp, vT, Qlen, Vlen, out);
}